// Round 1
// baseline (17048.096 us; speedup 1.0000x reference)
//
#include <hip/hip_runtime.h>

#define N_LINKS 262144
#define N_PAIRS 4194304
#define F 20
#define T_ITERS 4

__device__ __forceinline__ float selu_f(float x) {
    const float scale = 1.0507009873554805f;
    const float scale_alpha = 1.7580993408473766f;  // scale * alpha
    return x > 0.0f ? scale * x : scale_alpha * (__expf(x) - 1.0f);
}

__device__ __forceinline__ float sigmoid_f(float x) {
    return 1.0f / (1.0f + __expf(-x));
}

__device__ __forceinline__ float tanh_fast(float x) {
    x = fminf(fmaxf(x, -15.0f), 15.0f);
    float e = __expf(2.0f * x);
    return (e - 1.0f) / (e + 1.0f);
}

// Per link: X1[l] = W1 @ state[l] + b_msg ; X2[l] = W2 @ state[l] ; agg[l] = 0
__global__ void k_premsg(const float* __restrict__ state,
                         const float* __restrict__ W_msg,
                         const float* __restrict__ b_msg,
                         float* __restrict__ X1, float* __restrict__ X2,
                         float* __restrict__ agg) {
    __shared__ float Wl[F * 2 * F];   // 800 floats
    __shared__ float bl[F];
    for (int i = threadIdx.x; i < F * 2 * F; i += blockDim.x) Wl[i] = W_msg[i];
    if (threadIdx.x < F) bl[threadIdx.x] = b_msg[threadIdx.x];
    __syncthreads();

    int l = blockIdx.x * blockDim.x + threadIdx.x;
    if (l >= N_LINKS) return;

    float s[F];
    const float4* sp = (const float4*)(state + (size_t)l * F);
#pragma unroll
    for (int i = 0; i < 5; ++i) {
        float4 v = sp[i];
        s[4 * i + 0] = v.x; s[4 * i + 1] = v.y; s[4 * i + 2] = v.z; s[4 * i + 3] = v.w;
    }

    float o1[F], o2[F];
#pragma unroll
    for (int o = 0; o < F; ++o) {
        float a1 = bl[o];
        float a2 = 0.0f;
#pragma unroll
        for (int k = 0; k < F; ++k) {
            a1 = fmaf(Wl[o * 2 * F + k],     s[k], a1);
            a2 = fmaf(Wl[o * 2 * F + F + k], s[k], a2);
        }
        o1[o] = a1; o2[o] = a2;
    }

    float4* x1p = (float4*)(X1 + (size_t)l * F);
    float4* x2p = (float4*)(X2 + (size_t)l * F);
    float4* ap  = (float4*)(agg + (size_t)l * F);
    float4 z4 = make_float4(0.f, 0.f, 0.f, 0.f);
#pragma unroll
    for (int i = 0; i < 5; ++i) {
        x1p[i] = make_float4(o1[4*i], o1[4*i+1], o1[4*i+2], o1[4*i+3]);
        x2p[i] = make_float4(o2[4*i], o2[4*i+1], o2[4*i+2], o2[4*i+3]);
        ap[i]  = z4;
    }
}

// Per pair: agg[second] += selu(X1[first] + X2[second])
__global__ void k_msg_scatter(const int* __restrict__ first,
                              const int* __restrict__ second,
                              const float* __restrict__ X1,
                              const float* __restrict__ X2,
                              float* __restrict__ agg) {
    int p = blockIdx.x * blockDim.x + threadIdx.x;
    if (p >= N_PAIRS) return;
    int a = first[p];
    int b = second[p];
    const float4* xa = (const float4*)(X1 + (size_t)a * F);
    const float4* xb = (const float4*)(X2 + (size_t)b * F);
    float* dst = agg + (size_t)b * F;
#pragma unroll
    for (int i = 0; i < 5; ++i) {
        float4 va = xa[i];
        float4 vb = xb[i];
        atomicAdd(dst + 4 * i + 0, selu_f(va.x + vb.x));
        atomicAdd(dst + 4 * i + 1, selu_f(va.y + vb.y));
        atomicAdd(dst + 4 * i + 2, selu_f(va.z + vb.z));
        atomicAdd(dst + 4 * i + 3, selu_f(va.w + vb.w));
    }
}

// Per link: GRU cell  h' = (1-z)*n + z*h
__global__ void k_gru(const float* __restrict__ agg,
                      const float* __restrict__ h_in,
                      const float* __restrict__ W_ih,
                      const float* __restrict__ W_hh,
                      const float* __restrict__ b_ih,
                      const float* __restrict__ b_hh,
                      float* __restrict__ h_out) {
    __shared__ float Wi[3 * F * F];
    __shared__ float Wh[3 * F * F];
    __shared__ float bi[3 * F];
    __shared__ float bh[3 * F];
    for (int i = threadIdx.x; i < 3 * F * F; i += blockDim.x) {
        Wi[i] = W_ih[i];
        Wh[i] = W_hh[i];
    }
    if (threadIdx.x < 3 * F) {
        bi[threadIdx.x] = b_ih[threadIdx.x];
        bh[threadIdx.x] = b_hh[threadIdx.x];
    }
    __syncthreads();

    int l = blockIdx.x * blockDim.x + threadIdx.x;
    if (l >= N_LINKS) return;

    float m[F], h[F];
    const float4* mp = (const float4*)(agg  + (size_t)l * F);
    const float4* hp = (const float4*)(h_in + (size_t)l * F);
#pragma unroll
    for (int i = 0; i < 5; ++i) {
        float4 vm = mp[i], vh = hp[i];
        m[4*i+0] = vm.x; m[4*i+1] = vm.y; m[4*i+2] = vm.z; m[4*i+3] = vm.w;
        h[4*i+0] = vh.x; h[4*i+1] = vh.y; h[4*i+2] = vh.z; h[4*i+3] = vh.w;
    }

    float hn[F];
#pragma unroll
    for (int j = 0; j < F; ++j) {
        float gr = bi[j]         + bh[j];
        float gz = bi[F + j]     + bh[F + j];
        float gi_n = bi[2*F + j];
        float gh_n = bh[2*F + j];
        float gr_h = 0.f, gz_h = 0.f;
        // split: r,z need (i_x + h_x) sums; n needs i_n and h_n separately
        float gr_i = 0.f, gz_i = 0.f;
#pragma unroll
        for (int k = 0; k < F; ++k) {
            gr_i = fmaf(Wi[(0*F + j) * F + k], m[k], gr_i);
            gz_i = fmaf(Wi[(1*F + j) * F + k], m[k], gz_i);
            gi_n = fmaf(Wi[(2*F + j) * F + k], m[k], gi_n);
            gr_h = fmaf(Wh[(0*F + j) * F + k], h[k], gr_h);
            gz_h = fmaf(Wh[(1*F + j) * F + k], h[k], gz_h);
            gh_n = fmaf(Wh[(2*F + j) * F + k], h[k], gh_n);
        }
        float r = sigmoid_f(gr + gr_i + gr_h);
        float z = sigmoid_f(gz + gz_i + gz_h);
        float n = tanh_fast(gi_n + r * gh_n);
        hn[j] = (1.0f - z) * n + z * h[j];
    }

    float4* op = (float4*)(h_out + (size_t)l * F);
#pragma unroll
    for (int i = 0; i < 5; ++i)
        op[i] = make_float4(hn[4*i], hn[4*i+1], hn[4*i+2], hn[4*i+3]);
}

// feature[f] = sum over links of state[l][f].  blockDim = 320 (=16*20, 5 waves):
// flat element index i has feature i%20; stride (grid*320) % 20 == 0 so each
// thread's feature index is static and loads are perfectly coalesced.
__global__ void k_reduce(const float* __restrict__ state, float* __restrict__ feature) {
    __shared__ float lds[320];
    float acc = 0.0f;
    const long total = (long)N_LINKS * F;
    for (long i = (long)blockIdx.x * 320 + threadIdx.x; i < total; i += (long)gridDim.x * 320) {
        acc += state[i];
    }
    lds[threadIdx.x] = acc;
    __syncthreads();
    if (threadIdx.x < F) {
        float s = 0.0f;
#pragma unroll
        for (int g = 0; g < 16; ++g) s += lds[g * F + threadIdx.x];
        atomicAdd(feature + threadIdx.x, s);
    }
}

__global__ void k_readout(const float* __restrict__ feature,
                          const float* __restrict__ W_r1, const float* __restrict__ b_r1,
                          const float* __restrict__ W_r2, const float* __restrict__ b_r2,
                          const float* __restrict__ W_out, const float* __restrict__ b_out,
                          float* __restrict__ out) {
    if (threadIdx.x != 0 || blockIdx.x != 0) return;
    float fv[F], h1[F], h2[F];
#pragma unroll
    for (int i = 0; i < F; ++i) fv[i] = feature[i];
#pragma unroll
    for (int o = 0; o < F; ++o) {
        float a = b_r1[o];
#pragma unroll
        for (int k = 0; k < F; ++k) a = fmaf(W_r1[o * F + k], fv[k], a);
        h1[o] = selu_f(a);
    }
#pragma unroll
    for (int o = 0; o < F; ++o) {
        float a = b_r2[o];
#pragma unroll
        for (int k = 0; k < F; ++k) a = fmaf(W_r2[o * F + k], h1[k], a);
        h2[o] = selu_f(a);
    }
    float a = b_out[0];
#pragma unroll
    for (int k = 0; k < F; ++k) a = fmaf(W_out[k], h2[k], a);
    out[0] = a;
}

extern "C" void kernel_launch(void* const* d_in, const int* in_sizes, int n_in,
                              void* d_out, int out_size, void* d_ws, size_t ws_size,
                              hipStream_t stream) {
    const float* link_state = (const float*)d_in[0];
    const int*   first      = (const int*)  d_in[1];
    const int*   second     = (const int*)  d_in[2];
    // d_in[3] = state_dim (unused)
    const float* W_msg = (const float*)d_in[4];
    const float* b_msg = (const float*)d_in[5];
    const float* W_ih  = (const float*)d_in[6];
    const float* W_hh  = (const float*)d_in[7];
    const float* b_ih  = (const float*)d_in[8];
    const float* b_hh  = (const float*)d_in[9];
    const float* W_r1  = (const float*)d_in[10];
    const float* b_r1  = (const float*)d_in[11];
    const float* W_r2  = (const float*)d_in[12];
    const float* b_r2  = (const float*)d_in[13];
    const float* W_out = (const float*)d_in[14];
    const float* b_out = (const float*)d_in[15];
    float* out = (float*)d_out;

    float* state   = (float*)d_ws;                 // 20 MB
    float* X1      = state + (size_t)N_LINKS * F;  // 20 MB
    float* X2      = X1    + (size_t)N_LINKS * F;  // 20 MB
    float* agg     = X2    + (size_t)N_LINKS * F;  // 20 MB
    float* feature = agg   + (size_t)N_LINKS * F;  // 80 B

    for (int t = 0; t < T_ITERS; ++t) {
        const float* h = (t == 0) ? link_state : state;
        k_premsg<<<N_LINKS / 256, 256, 0, stream>>>(h, W_msg, b_msg, X1, X2, agg);
        k_msg_scatter<<<N_PAIRS / 256, 256, 0, stream>>>(first, second, X1, X2, agg);
        k_gru<<<N_LINKS / 256, 256, 0, stream>>>(agg, h, W_ih, W_hh, b_ih, b_hh, state);
    }
    hipMemsetAsync(feature, 0, F * sizeof(float), stream);
    k_reduce<<<512, 320, 0, stream>>>(state, feature);
    k_readout<<<1, 64, 0, stream>>>(feature, W_r1, b_r1, W_r2, b_r2, W_out, b_out, out);
}

// Round 2
// 1610.473 us; speedup vs baseline: 10.5858x; 10.5858x over previous
//
#include <hip/hip_runtime.h>

#define N_LINKS 262144
#define N_PAIRS 4194304
#define F 20
#define T_ITERS 4

__device__ __forceinline__ float selu_f(float x) {
    const float scale = 1.0507009873554805f;
    const float scale_alpha = 1.7580993408473766f;  // scale * alpha
    return x > 0.0f ? scale * x : scale_alpha * (__expf(x) - 1.0f);
}

__device__ __forceinline__ float sigmoid_f(float x) {
    return 1.0f / (1.0f + __expf(-x));
}

__device__ __forceinline__ float tanh_fast(float x) {
    x = fminf(fmaxf(x, -15.0f), 15.0f);
    float e = __expf(2.0f * x);
    return (e - 1.0f) / (e + 1.0f);
}

// ---------------- CSR build (once per call; graph is static) ----------------

__global__ void k_hist(const int* __restrict__ second, int* __restrict__ counts) {
    int p = blockIdx.x * blockDim.x + threadIdx.x;
    if (p < N_PAIRS) atomicAdd(&counts[second[p]], 1);
}

// Single-block exclusive scan over 262144 counts -> rs[0..N_LINKS], cursor copy.
__global__ void k_scan(const int* __restrict__ counts,
                       int* __restrict__ rs, int* __restrict__ cursor) {
    __shared__ int sums[1024];
    const int tid = threadIdx.x;
    const int PER = N_LINKS / 1024;  // 256
    const int base = tid * PER;
    int s = 0;
    for (int i = 0; i < PER; ++i) s += counts[base + i];
    sums[tid] = s;
    __syncthreads();
    for (int off = 1; off < 1024; off <<= 1) {
        int v = (tid >= off) ? sums[tid - off] : 0;
        __syncthreads();
        sums[tid] += v;
        __syncthreads();
    }
    int run = (tid == 0) ? 0 : sums[tid - 1];
    for (int i = 0; i < PER; ++i) {
        rs[base + i] = run;
        cursor[base + i] = run;
        run += counts[base + i];
    }
    if (tid == 1023) rs[N_LINKS] = run;
}

__global__ void k_fill(const int* __restrict__ first, const int* __restrict__ second,
                       int* __restrict__ cursor, int* __restrict__ first_sorted) {
    int p = blockIdx.x * blockDim.x + threadIdx.x;
    if (p >= N_PAIRS) return;
    int pos = atomicAdd(&cursor[second[p]], 1);
    first_sorted[pos] = first[p];
}

// ---------------- per-iteration kernels ----------------

// Per link: X1[l] = W1 @ state[l] + b_msg ; X2[l] = W2 @ state[l]
__global__ void k_premsg(const float* __restrict__ state,
                         const float* __restrict__ W_msg,
                         const float* __restrict__ b_msg,
                         float* __restrict__ X1, float* __restrict__ X2) {
    __shared__ float Wl[F * 2 * F];   // 800 floats
    __shared__ float bl[F];
    for (int i = threadIdx.x; i < F * 2 * F; i += blockDim.x) Wl[i] = W_msg[i];
    if (threadIdx.x < F) bl[threadIdx.x] = b_msg[threadIdx.x];
    __syncthreads();

    int l = blockIdx.x * blockDim.x + threadIdx.x;
    if (l >= N_LINKS) return;

    float s[F];
    const float4* sp = (const float4*)(state + (size_t)l * F);
#pragma unroll
    for (int i = 0; i < 5; ++i) {
        float4 v = sp[i];
        s[4 * i + 0] = v.x; s[4 * i + 1] = v.y; s[4 * i + 2] = v.z; s[4 * i + 3] = v.w;
    }

    float o1[F], o2[F];
#pragma unroll
    for (int o = 0; o < F; ++o) {
        float a1 = bl[o];
        float a2 = 0.0f;
#pragma unroll
        for (int k = 0; k < F; ++k) {
            a1 = fmaf(Wl[o * 2 * F + k],     s[k], a1);
            a2 = fmaf(Wl[o * 2 * F + F + k], s[k], a2);
        }
        o1[o] = a1; o2[o] = a2;
    }

    float4* x1p = (float4*)(X1 + (size_t)l * F);
    float4* x2p = (float4*)(X2 + (size_t)l * F);
#pragma unroll
    for (int i = 0; i < 5; ++i) {
        x1p[i] = make_float4(o1[4*i], o1[4*i+1], o1[4*i+2], o1[4*i+3]);
        x2p[i] = make_float4(o2[4*i], o2[4*i+1], o2[4*i+2], o2[4*i+3]);
    }
}

// Gather-aggregate: one wave64 per destination link.
// 3 subgroups of 20 lanes (lane = g*20+f); subgroup g walks pairs rs[l]+g,
// +3, ... ; each subgroup's 20 lanes read one contiguous 80B X1 row.
// agg[l][f] = sum_p selu(X1[first_sorted[p]][f] + X2[l][f])
__global__ void k_agg(const int* __restrict__ rs,
                      const int* __restrict__ first_sorted,
                      const float* __restrict__ X1,
                      const float* __restrict__ X2,
                      float* __restrict__ agg) {
    const int wave = threadIdx.x >> 6;                 // 4 waves/block
    const int l = blockIdx.x * 4 + wave;
    const int lane = threadIdx.x & 63;
    const int g = lane / F;                            // 0..3 (g==3 idle)
    const int f = lane % F;

    const float x2f = X2[(size_t)l * F + f];
    const int row_start = rs[l];
    const int row_end = rs[l + 1];

    float acc = 0.0f;
    if (g < 3) {
        for (int p = row_start + g; p < row_end; p += 3) {
            int a = first_sorted[p];
            float x1 = X1[(size_t)a * F + f];
            acc += selu_f(x1 + x2f);
        }
    }
    // reduce the 3 subgroups onto lanes 0..19
    float a1 = __shfl(acc, (lane + 20) & 63, 64);
    float a2 = __shfl(acc, (lane + 40) & 63, 64);
    if (lane < F) agg[(size_t)l * F + lane] = acc + a1 + a2;
}

// Per link: GRU cell  h' = (1-z)*n + z*h
__global__ void k_gru(const float* __restrict__ agg,
                      const float* __restrict__ h_in,
                      const float* __restrict__ W_ih,
                      const float* __restrict__ W_hh,
                      const float* __restrict__ b_ih,
                      const float* __restrict__ b_hh,
                      float* __restrict__ h_out) {
    __shared__ float Wi[3 * F * F];
    __shared__ float Wh[3 * F * F];
    __shared__ float bi[3 * F];
    __shared__ float bh[3 * F];
    for (int i = threadIdx.x; i < 3 * F * F; i += blockDim.x) {
        Wi[i] = W_ih[i];
        Wh[i] = W_hh[i];
    }
    if (threadIdx.x < 3 * F) {
        bi[threadIdx.x] = b_ih[threadIdx.x];
        bh[threadIdx.x] = b_hh[threadIdx.x];
    }
    __syncthreads();

    int l = blockIdx.x * blockDim.x + threadIdx.x;
    if (l >= N_LINKS) return;

    float m[F], h[F];
    const float4* mp = (const float4*)(agg  + (size_t)l * F);
    const float4* hp = (const float4*)(h_in + (size_t)l * F);
#pragma unroll
    for (int i = 0; i < 5; ++i) {
        float4 vm = mp[i], vh = hp[i];
        m[4*i+0] = vm.x; m[4*i+1] = vm.y; m[4*i+2] = vm.z; m[4*i+3] = vm.w;
        h[4*i+0] = vh.x; h[4*i+1] = vh.y; h[4*i+2] = vh.z; h[4*i+3] = vh.w;
    }

    float hn[F];
#pragma unroll
    for (int j = 0; j < F; ++j) {
        float gr = bi[j]         + bh[j];
        float gz = bi[F + j]     + bh[F + j];
        float gi_n = bi[2*F + j];
        float gh_n = bh[2*F + j];
        float gr_i = 0.f, gz_i = 0.f, gr_h = 0.f, gz_h = 0.f;
#pragma unroll
        for (int k = 0; k < F; ++k) {
            gr_i = fmaf(Wi[(0*F + j) * F + k], m[k], gr_i);
            gz_i = fmaf(Wi[(1*F + j) * F + k], m[k], gz_i);
            gi_n = fmaf(Wi[(2*F + j) * F + k], m[k], gi_n);
            gr_h = fmaf(Wh[(0*F + j) * F + k], h[k], gr_h);
            gz_h = fmaf(Wh[(1*F + j) * F + k], h[k], gz_h);
            gh_n = fmaf(Wh[(2*F + j) * F + k], h[k], gh_n);
        }
        float r = sigmoid_f(gr + gr_i + gr_h);
        float z = sigmoid_f(gz + gz_i + gz_h);
        float n = tanh_fast(gi_n + r * gh_n);
        hn[j] = (1.0f - z) * n + z * h[j];
    }

    float4* op = (float4*)(h_out + (size_t)l * F);
#pragma unroll
    for (int i = 0; i < 5; ++i)
        op[i] = make_float4(hn[4*i], hn[4*i+1], hn[4*i+2], hn[4*i+3]);
}

// feature[f] = sum over links of state[l][f].
__global__ void k_reduce(const float* __restrict__ state, float* __restrict__ feature) {
    __shared__ float lds[320];
    float acc = 0.0f;
    const long total = (long)N_LINKS * F;
    for (long i = (long)blockIdx.x * 320 + threadIdx.x; i < total; i += (long)gridDim.x * 320) {
        acc += state[i];
    }
    lds[threadIdx.x] = acc;
    __syncthreads();
    if (threadIdx.x < F) {
        float s = 0.0f;
#pragma unroll
        for (int g = 0; g < 16; ++g) s += lds[g * F + threadIdx.x];
        atomicAdd(feature + threadIdx.x, s);
    }
}

__global__ void k_readout(const float* __restrict__ feature,
                          const float* __restrict__ W_r1, const float* __restrict__ b_r1,
                          const float* __restrict__ W_r2, const float* __restrict__ b_r2,
                          const float* __restrict__ W_out, const float* __restrict__ b_out,
                          float* __restrict__ out) {
    if (threadIdx.x != 0 || blockIdx.x != 0) return;
    float fv[F], h1[F], h2[F];
#pragma unroll
    for (int i = 0; i < F; ++i) fv[i] = feature[i];
#pragma unroll
    for (int o = 0; o < F; ++o) {
        float a = b_r1[o];
#pragma unroll
        for (int k = 0; k < F; ++k) a = fmaf(W_r1[o * F + k], fv[k], a);
        h1[o] = selu_f(a);
    }
#pragma unroll
    for (int o = 0; o < F; ++o) {
        float a = b_r2[o];
#pragma unroll
        for (int k = 0; k < F; ++k) a = fmaf(W_r2[o * F + k], h1[k], a);
        h2[o] = selu_f(a);
    }
    float a = b_out[0];
#pragma unroll
    for (int k = 0; k < F; ++k) a = fmaf(W_out[k], h2[k], a);
    out[0] = a;
}

extern "C" void kernel_launch(void* const* d_in, const int* in_sizes, int n_in,
                              void* d_out, int out_size, void* d_ws, size_t ws_size,
                              hipStream_t stream) {
    const float* link_state = (const float*)d_in[0];
    const int*   first      = (const int*)  d_in[1];
    const int*   second     = (const int*)  d_in[2];
    // d_in[3] = state_dim (unused)
    const float* W_msg = (const float*)d_in[4];
    const float* b_msg = (const float*)d_in[5];
    const float* W_ih  = (const float*)d_in[6];
    const float* W_hh  = (const float*)d_in[7];
    const float* b_ih  = (const float*)d_in[8];
    const float* b_hh  = (const float*)d_in[9];
    const float* W_r1  = (const float*)d_in[10];
    const float* b_r1  = (const float*)d_in[11];
    const float* W_r2  = (const float*)d_in[12];
    const float* b_r2  = (const float*)d_in[13];
    const float* W_out = (const float*)d_in[14];
    const float* b_out = (const float*)d_in[15];
    float* out = (float*)d_out;

    float* state   = (float*)d_ws;                  // 20.97 MB
    float* X1      = state + (size_t)N_LINKS * F;   // 20.97 MB
    float* X2      = X1    + (size_t)N_LINKS * F;   // 20.97 MB
    float* agg     = X2    + (size_t)N_LINKS * F;   // 20.97 MB
    float* feature = agg   + (size_t)N_LINKS * F;   // 128 B slot
    int* counts       = (int*)(feature + 32);       // 1 MB
    int* rs           = counts + N_LINKS;           // 1 MB (+1)
    int* cursor       = rs + N_LINKS + 1;           // 1 MB
    int* first_sorted = cursor + N_LINKS;           // 16.78 MB

    // ---- CSR build (graph static across iterations) ----
    hipMemsetAsync(counts, 0, N_LINKS * sizeof(int), stream);
    k_hist<<<N_PAIRS / 256, 256, 0, stream>>>(second, counts);
    k_scan<<<1, 1024, 0, stream>>>(counts, rs, cursor);
    k_fill<<<N_PAIRS / 256, 256, 0, stream>>>(first, second, cursor, first_sorted);

    for (int t = 0; t < T_ITERS; ++t) {
        const float* h = (t == 0) ? link_state : state;
        k_premsg<<<N_LINKS / 256, 256, 0, stream>>>(h, W_msg, b_msg, X1, X2);
        k_agg<<<N_LINKS / 4, 256, 0, stream>>>(rs, first_sorted, X1, X2, agg);
        k_gru<<<N_LINKS / 256, 256, 0, stream>>>(agg, h, W_ih, W_hh, b_ih, b_hh, state);
    }
    hipMemsetAsync(feature, 0, F * sizeof(float), stream);
    k_reduce<<<512, 320, 0, stream>>>(state, feature);
    k_readout<<<1, 64, 0, stream>>>(feature, W_r1, b_r1, W_r2, b_r2, W_out, b_out, out);
}